// Round 12
// baseline (716.713 us; speedup 1.0000x reference)
//
#include <hip/hip_runtime.h>
#include <hip/hip_bf16.h>

// NewellGRUModel: B=512, S=1024, F=16, H=64.  bf16 in/out (proven r2..r11).
//
// MFMA restructure: 32 blocks x 256 thr (4 waves). Block owns 16 batches;
// wave wv owns units [16wv,16wv+16) = 3 B-tiles (z/r/hh). Per step:
// gates = [h_hi | h_lo | x] (K=64+64+32) @ W via 15 v_mfma_f32_16x16x32_bf16
// per wave. h carried fp32; fed to MFMA as hi+lo bf16 split (fp32-grade).
// Fragment layouts (HW-verified per guide): A: m=lane&15, k=quad*8+j;
// B: n=lane&15, k=quad*8+j; C/D: col(unit)=lane&15, row(batch)=quad*4+reg.
// z,r,hh for a (batch,unit) land in the same lane -> local nonlinearity,
// zero shuffles. h exchanged via pad-66 LDS (parity dbuf), 1 barrier/step.
// Biases folded into accumulator init. x-chunk B rows >=15 are zero (ch15
// excluded from GRU input; ch15 feeds dsum during staging).

typedef __bf16 bf16x8 __attribute__((ext_vector_type(8)));
typedef float  f32x4  __attribute__((ext_vector_type(4)));

union BFU { unsigned short s; __bf16 b; };
union FIU { unsigned int u; float f; };

__device__ __forceinline__ __bf16 us2bf(unsigned short s) { BFU u; u.s = s; return u.b; }

template<bool BF16>
struct IO {
    static __device__ __forceinline__ float ld(const void* p, int i) {
        if constexpr (BF16) {
            FIU c; c.u = (unsigned int)((const unsigned short*)p)[i] << 16;
            return c.f;
        } else {
            return ((const float*)p)[i];
        }
    }
    static __device__ __forceinline__ __bf16 ldb(const void* p, int i) {
        if constexpr (BF16) {
            return us2bf(((const unsigned short*)p)[i]);   // exact bits
        } else {
            return (__bf16)((const float*)p)[i];           // lossy; fp32 path never runs
        }
    }
    static __device__ __forceinline__ void st(void* p, int i, float v) {
        if constexpr (BF16) ((__hip_bfloat16*)p)[i] = __float2bfloat16(v);
        else ((float*)p)[i] = v;
    }
};

// Stage one (s2-row, batch) = 16 channels as packed bf16 bits (2 x uint4).
template<bool BF16>
__device__ __forceinline__ void stagex(const void* inp, size_t idx, uint4& A, uint4& B) {
    if constexpr (BF16) {
        const uint4* p = (const uint4*)((const unsigned short*)inp + idx);
        A = p[0]; B = p[1];
    } else {
        const float* f = (const float*)inp + idx;
        FIU c; unsigned int us[16];
#pragma unroll
        for (int j = 0; j < 16; ++j) { c.f = f[j]; us[j] = c.u >> 16; }
        A.x = us[0]  | (us[1]  << 16); A.y = us[2]  | (us[3]  << 16);
        A.z = us[4]  | (us[5]  << 16); A.w = us[6]  | (us[7]  << 16);
        B.x = us[8]  | (us[9]  << 16); B.y = us[10] | (us[11] << 16);
        B.z = us[12] | (us[13] << 16); B.w = us[14] | (us[15] << 16);
    }
}

// mode: 0 = buffers are bf16, 1 = buffers are fp32.
__global__ void detect_dtype_kernel(const void* rkbuf, int* flag) {
    const float* f = (const float*)rkbuf;
    int ok = 0;
    for (int i = 0; i < 64; ++i) {
        float a = fabsf(f[i]);
        ok += (a > 1e-5f && a < 2.0f) ? 1 : 0;
    }
    *flag = (ok >= 48) ? 1 : 0;
}

template<bool BF16>
__global__ __launch_bounds__(256, 1)
void gru_full_kernel(const void* __restrict__ inp, const void* __restrict__ gk,
                     const void* __restrict__ rk,  const void* __restrict__ gb,
                     const void* __restrict__ w1,  const void* __restrict__ b1v,
                     const void* __restrict__ gam, const void* __restrict__ bet,
                     const void* __restrict__ muv, const void* __restrict__ vav,
                     const void* __restrict__ w2,  const void* __restrict__ bb2,
                     const void* __restrict__ Tp,  const int* __restrict__ mode,
                     void* __restrict__ out)
{
    const int want = BF16 ? 0 : 1;
    if (*mode != want) return;

    const int g   = blockIdx.x;        // batch group: batches 16g..16g+15
    const int tid = threadIdx.x;       // 0..255
    const int wv  = tid >> 6;          // wave 0..3 -> unit slice [16wv, +16)
    const int l   = tid & 63;
    const int q   = l >> 4;            // quad 0..3
    const int lc  = l & 15;            // A-row (batch) for reads / B-col (unit-local)
    const int u   = 16 * wv + lc;      // this lane's global unit (B column)

    __shared__ __align__(16) unsigned short xt[2][16][16][16]; // [buf][s2][batch][ch]
    __shared__ __align__(16) float hsm[2][16][66];             // [par][batch][unit(pad66)]
    __shared__ __align__(16) float dred[16][16];               // [s2-part][batch]

    using io = IO<BF16>;

    // ---- B fragments (loop-invariant; AGPR parking is fine for MFMA) ----
    bf16x8 Bz0, Bz1, Br0, Br1, Bh0, Bh1, Bxz, Bxr, Bxh;
#pragma unroll
    for (int j = 0; j < 8; ++j) {
        const int k0 = 8 * q + j;      // W rows 0..31
        const int k1 = 32 + k0;        // W rows 32..63
        Bz0[j] = io::ldb(rk, k0 * 192 + u);
        Bz1[j] = io::ldb(rk, k1 * 192 + u);
        Br0[j] = io::ldb(rk, k0 * 192 + 64 + u);
        Br1[j] = io::ldb(rk, k1 * 192 + 64 + u);
        Bh0[j] = io::ldb(rk, k0 * 192 + 128 + u);
        Bh1[j] = io::ldb(rk, k1 * 192 + 128 + u);
        const bool vx = (k0 < 15);     // x rows 15..31 are zero (ch15 excluded)
        Bxz[j] = vx ? io::ldb(gk, k0 * 192 + u)       : us2bf(0);
        Bxr[j] = vx ? io::ldb(gk, k0 * 192 + 64 + u)  : us2bf(0);
        Bxh[j] = vx ? io::ldb(gk, k0 * 192 + 128 + u) : us2bf(0);
    }
    // biases for this lane's unit (folded into accumulator init)
    const float bz_  = io::ld(gb, u)        + io::ld(gb, 192 + u);
    const float br_  = io::ld(gb, 64 + u)   + io::ld(gb, 192 + 64 + u);
    const float bah_ = io::ld(gb, 192 + 128 + u);   // b_r[h] (inside r*rh)
    const float bax_ = io::ld(gb, 128 + u);         // b_i[h]

    // zero-init h parity 0
    {
        float* hz = &hsm[0][0][0];
        for (int i = tid; i < 16 * 66; i += 256) hz[i] = 0.0f;
    }
    float hreg[4] = {0.0f, 0.0f, 0.0f, 0.0f};   // h for batches 4q+i, unit u

    // staging mapping: thread -> (batch sb, s2-row sp)
    const int sb = tid >> 4, sp = tid & 15;
    const size_t gbase = (size_t)(16 * g + sb) * 16384;
    uint4 rA, rB;
    stagex<BF16>(inp, gbase + (size_t)sp * 16, rA, rB);   // tile 0
    float dsumP = 0.0f;

#pragma unroll 1
    for (int t = 0; t < 64; ++t) {
        *(uint4*)&xt[t & 1][sp][sb][0] = rA;
        *(uint4*)&xt[t & 1][sp][sb][8] = rB;
        dsumP += (float)us2bf((unsigned short)(rB.w >> 16));   // ch15 of this row
        __syncthreads();
        if (t < 63) stagex<BF16>(inp, gbase + (size_t)(16 * (t + 1) + sp) * 16, rA, rB);

#pragma unroll 2
        for (int s2 = 0; s2 < 16; ++s2) {
            const int s   = 16 * t + s2;
            const int par = s & 1;

            // ---- A (h) read: 8x ds_read_b64 from pad-66 rows ----
            float hv[16];
            const float* hrow = &hsm[par][lc][0];
#pragma unroll
            for (int d = 0; d < 4; ++d) {
                const float2 e = *(const float2*)(hrow + 8 * q + 2 * d);
                hv[2 * d] = e.x; hv[2 * d + 1] = e.y;
            }
#pragma unroll
            for (int d = 0; d < 4; ++d) {
                const float2 e = *(const float2*)(hrow + 32 + 8 * q + 2 * d);
                hv[8 + 2 * d] = e.x; hv[8 + 2 * d + 1] = e.y;
            }
            // ---- hi/lo bf16 split (fp32-grade accuracy) ----
            bf16x8 Ahi0, Alo0, Ahi1, Alo1;
#pragma unroll
            for (int j = 0; j < 8; ++j) {
                const __bf16 h0 = (__bf16)hv[j];
                Ahi0[j] = h0;
                Alo0[j] = (__bf16)(hv[j] - (float)h0);
                const __bf16 h1 = (__bf16)hv[8 + j];
                Ahi1[j] = h1;
                Alo1[j] = (__bf16)(hv[8 + j] - (float)h1);
            }
            // ---- A (x) fragment: quads 0,1 carry ch0..15; quads 2,3 zero ----
            const uint4 xa = *(const uint4*)&xt[t & 1][s2][lc][8 * (q & 1)];
            const bool xv = (q < 2);
            const unsigned int w0 = xv ? xa.x : 0u, w1_ = xv ? xa.y : 0u;
            const unsigned int w2_ = xv ? xa.z : 0u, w3_ = xv ? xa.w : 0u;
            bf16x8 Ax;
            Ax[0] = us2bf((unsigned short)(w0 & 0xffff));  Ax[1] = us2bf((unsigned short)(w0 >> 16));
            Ax[2] = us2bf((unsigned short)(w1_ & 0xffff)); Ax[3] = us2bf((unsigned short)(w1_ >> 16));
            Ax[4] = us2bf((unsigned short)(w2_ & 0xffff)); Ax[5] = us2bf((unsigned short)(w2_ >> 16));
            Ax[6] = us2bf((unsigned short)(w3_ & 0xffff)); Ax[7] = us2bf((unsigned short)(w3_ >> 16));

            // ---- 15 MFMAs, split chains (depth 3) ----
            f32x4 azA, azB, arA, arB, ahA, ahB, axA;
#pragma unroll
            for (int i = 0; i < 4; ++i) {
                azA[i] = bz_;  azB[i] = 0.0f;
                arA[i] = br_;  arB[i] = 0.0f;
                ahA[i] = bah_; ahB[i] = 0.0f;
                axA[i] = bax_;
            }
            azA = __builtin_amdgcn_mfma_f32_16x16x32_bf16(Ahi0, Bz0, azA, 0, 0, 0);
            azA = __builtin_amdgcn_mfma_f32_16x16x32_bf16(Alo0, Bz0, azA, 0, 0, 0);
            azB = __builtin_amdgcn_mfma_f32_16x16x32_bf16(Ahi1, Bz1, azB, 0, 0, 0);
            azB = __builtin_amdgcn_mfma_f32_16x16x32_bf16(Alo1, Bz1, azB, 0, 0, 0);
            azB = __builtin_amdgcn_mfma_f32_16x16x32_bf16(Ax,   Bxz, azB, 0, 0, 0);
            arA = __builtin_amdgcn_mfma_f32_16x16x32_bf16(Ahi0, Br0, arA, 0, 0, 0);
            arA = __builtin_amdgcn_mfma_f32_16x16x32_bf16(Alo0, Br0, arA, 0, 0, 0);
            arB = __builtin_amdgcn_mfma_f32_16x16x32_bf16(Ahi1, Br1, arB, 0, 0, 0);
            arB = __builtin_amdgcn_mfma_f32_16x16x32_bf16(Alo1, Br1, arB, 0, 0, 0);
            arB = __builtin_amdgcn_mfma_f32_16x16x32_bf16(Ax,   Bxr, arB, 0, 0, 0);
            ahA = __builtin_amdgcn_mfma_f32_16x16x32_bf16(Ahi0, Bh0, ahA, 0, 0, 0);
            ahA = __builtin_amdgcn_mfma_f32_16x16x32_bf16(Alo0, Bh0, ahA, 0, 0, 0);
            ahB = __builtin_amdgcn_mfma_f32_16x16x32_bf16(Ahi1, Bh1, ahB, 0, 0, 0);
            ahB = __builtin_amdgcn_mfma_f32_16x16x32_bf16(Alo1, Bh1, ahB, 0, 0, 0);
            axA = __builtin_amdgcn_mfma_f32_16x16x32_bf16(Ax,   Bxh, axA, 0, 0, 0);

            const f32x4 AZ = azA + azB;
            const f32x4 AR = arA + arB;
            const f32x4 AH = ahA + ahB;

            // ---- nonlinearity: lane holds (batch=4q+i, unit=u) ----
            const int pn = par ^ 1;
#pragma unroll
            for (int i = 0; i < 4; ++i) {
                const float z   = __builtin_amdgcn_rcpf(1.0f + __expf(-AZ[i]));
                const float r   = __builtin_amdgcn_rcpf(1.0f + __expf(-AR[i]));
                const float pre = fmaf(r, AH[i], axA[i]);
                const float e2  = __expf(2.0f * pre);
                const float th  = 1.0f - 2.0f * __builtin_amdgcn_rcpf(e2 + 1.0f);
                hreg[i] = fmaf(z, hreg[i] - th, th);
                hsm[pn][4 * q + i][u] = hreg[i];
            }
            __syncthreads();           // the ONE barrier per step
        }
    }

    // ---- epilogue: delta effect + dense head ----
    dred[sp][sb] = dsumP;
    __syncthreads();

    const int hb = tid >> 4, hr = tid & 15;   // (batch, j-part)
    float dsb = 0.0f;
#pragma unroll
    for (int pp = 0; pp < 16; ++pp) dsb += dred[pp][hb];
    const float de = io::ld(Tp, 0) * dsb * (1.0f / 1024.0f);

    float accj[4];
#pragma unroll
    for (int jj = 0; jj < 4; ++jj) accj[jj] = io::ld(b1v, hr + 16 * jj);
    for (int uu = 0; uu < 64; ++uu) {
        const float sv = hsm[0][hb][uu] + de;   // final parity = 0
#pragma unroll
        for (int jj = 0; jj < 4; ++jj)
            accj[jj] = fmaf(sv, io::ld(w1, uu * 64 + hr + 16 * jj), accj[jj]);
    }
    float part = 0.0f;
#pragma unroll
    for (int jj = 0; jj < 4; ++jj) {
        const int j = hr + 16 * jj;
        float aa = fmaxf(accj[jj], 0.0f);                      // ReLU
        const float inv = rsqrtf(io::ld(vav, j) + 0.001f);     // BN_EPS
        aa = fmaf((aa - io::ld(muv, j)) * inv, io::ld(gam, j), io::ld(bet, j));
        part = fmaf(aa, io::ld(w2, j), part);
    }
    part += __shfl_xor(part, 1, 64);
    part += __shfl_xor(part, 2, 64);
    part += __shfl_xor(part, 4, 64);
    part += __shfl_xor(part, 8, 64);
    if (hr == 0) io::st(out, 16 * g + hb, part + io::ld(bb2, 0));
}

extern "C" void kernel_launch(void* const* d_in, const int* in_sizes, int n_in,
                              void* d_out, int out_size, void* d_ws, size_t ws_size,
                              hipStream_t stream)
{
    const void* inp = d_in[0];   // (512,1024,16)
    const void* gk  = d_in[1];   // (15,192)
    const void* rk  = d_in[2];   // (64,192)
    const void* gb  = d_in[3];   // (2,192)
    const void* w1  = d_in[4];   // (64,64)
    const void* b1v = d_in[5];   // (64,)
    const void* gam = d_in[6];
    const void* bet = d_in[7];
    const void* muv = d_in[8];
    const void* vav = d_in[9];
    const void* w2  = d_in[10];  // (64,1)
    const void* bb2 = d_in[11];  // (1,)
    const void* Tp  = d_in[12];  // (1,)

    int* flag = (int*)d_ws;
    detect_dtype_kernel<<<dim3(1), dim3(1), 0, stream>>>(rk, flag);
    gru_full_kernel<true ><<<dim3(32), dim3(256), 0, stream>>>(
        inp, gk, rk, gb, w1, b1v, gam, bet, muv, vav, w2, bb2, Tp, flag, d_out);
    gru_full_kernel<false><<<dim3(32), dim3(256), 0, stream>>>(
        inp, gk, rk, gb, w1, b1v, gam, bet, muv, vav, w2, bb2, Tp, flag, d_out);
}

// Round 13
// 668.539 us; speedup vs baseline: 1.0721x; 1.0721x over previous
//
#include <hip/hip_runtime.h>
#include <hip/hip_bf16.h>

// NewellGRUModel: B=512, S=1024, F=16, H=64.  bf16 in/out.
//
// r12 (MFMA, correct, 648us) was latency-bound on VALU shoulder work around
// the MFMAs: per-step fp32->hi/lo split (~130 inst), Ax assembly, b64+unpack
// A-reads. r13: h stored in LDS as INTERLEAVED bf16 (hi,lo) pairs ->
// A-fragments are raw contiguous shorts (2x ds_read_b64 per K-tile, zero
// unpack); B-fragments duplicate each W row twice (k'=2u+p -> W[u]), built
// once at init. K=128 over the interleaved vector = 4 K-tiles x 3 gates
// + 3 x-MFMAs = 15 MFMAs (math identical to r12 -> same ~2e-3 absmax).
// x staged as zero-padded 36-short rows (A-frag = 2 raw ds_read_b64).
// All LDS strides chosen for <=2-way bank aliasing (free, m136).
// Split happens once at WRITE time (4x cvt/sub/pack + 4 ds_write_b32).
// Mapping (r12, proven): 32 blocks x 256 thr; block = 16 batches; wave wv
// owns units [16wv,+16); C/D row=batch=4q+i, col=unit (m89-verified);
// 1 barrier/step; parity-dbuf hsm.

typedef __bf16 bf16x8 __attribute__((ext_vector_type(8)));
typedef float  f32x4  __attribute__((ext_vector_type(4)));

union BFU { unsigned short s; __bf16 b; };
union FIU { unsigned int u; float f; };
union HBU { __hip_bfloat16 b; unsigned short s; };

__device__ __forceinline__ __bf16 us2bf(unsigned short s) { BFU u; u.s = s; return u.b; }

template<bool BF16>
struct IO {
    static __device__ __forceinline__ float ld(const void* p, int i) {
        if constexpr (BF16) {
            FIU c; c.u = (unsigned int)((const unsigned short*)p)[i] << 16;
            return c.f;
        } else {
            return ((const float*)p)[i];
        }
    }
    static __device__ __forceinline__ __bf16 ldb(const void* p, int i) {
        if constexpr (BF16) {
            return us2bf(((const unsigned short*)p)[i]);
        } else {
            return (__bf16)((const float*)p)[i];
        }
    }
    static __device__ __forceinline__ void st(void* p, int i, float v) {
        if constexpr (BF16) ((__hip_bfloat16*)p)[i] = __float2bfloat16(v);
        else ((float*)p)[i] = v;
    }
};

// Stage one (s2-row, batch) = 16 channels as packed bf16 bits (2 x uint4).
template<bool BF16>
__device__ __forceinline__ void stagex(const void* inp, size_t idx, uint4& A, uint4& B) {
    if constexpr (BF16) {
        const uint4* p = (const uint4*)((const unsigned short*)inp + idx);
        A = p[0]; B = p[1];
    } else {
        const float* f = (const float*)inp + idx;
        FIU c; unsigned int us[16];
#pragma unroll
        for (int j = 0; j < 16; ++j) { c.f = f[j]; us[j] = c.u >> 16; }
        A.x = us[0]  | (us[1]  << 16); A.y = us[2]  | (us[3]  << 16);
        A.z = us[4]  | (us[5]  << 16); A.w = us[6]  | (us[7]  << 16);
        B.x = us[8]  | (us[9]  << 16); B.y = us[10] | (us[11] << 16);
        B.z = us[12] | (us[13] << 16); B.w = us[14] | (us[15] << 16);
    }
}

// mode: 0 = buffers are bf16, 1 = buffers are fp32.
__global__ void detect_dtype_kernel(const void* rkbuf, int* flag) {
    const float* f = (const float*)rkbuf;
    int ok = 0;
    for (int i = 0; i < 64; ++i) {
        float a = fabsf(f[i]);
        ok += (a > 1e-5f && a < 2.0f) ? 1 : 0;
    }
    *flag = (ok >= 48) ? 1 : 0;
}

template<bool BF16>
__global__ __launch_bounds__(256, 1)
void gru_full_kernel(const void* __restrict__ inp, const void* __restrict__ gk,
                     const void* __restrict__ rk,  const void* __restrict__ gb,
                     const void* __restrict__ w1,  const void* __restrict__ b1v,
                     const void* __restrict__ gam, const void* __restrict__ bet,
                     const void* __restrict__ muv, const void* __restrict__ vav,
                     const void* __restrict__ w2,  const void* __restrict__ bb2,
                     const void* __restrict__ Tp,  const int* __restrict__ mode,
                     void* __restrict__ out)
{
    const int want = BF16 ? 0 : 1;
    if (*mode != want) return;

    const int g   = blockIdx.x;        // batch group: batches 16g..16g+15
    const int tid = threadIdx.x;       // 0..255
    const int wv  = tid >> 6;          // wave 0..3 -> unit slice [16wv, +16)
    const int l   = tid & 63;
    const int q   = l >> 4;            // quad 0..3
    const int lc  = l & 15;            // A-row (batch) / B-col (unit-local)
    const int u   = 16 * wv + lc;      // this lane's global unit

    // LDS: strides tuned for <=2-way bank aliasing with b64 reads.
    __shared__ __align__(16) unsigned short xt[2][16][16][36]; // [buf][s2][batch][ch-pad36]
    __shared__ __align__(16) unsigned short hsm[2][16][132];   // [par][batch][2u=hi,2u+1=lo]
    __shared__ __align__(16) float heb[16][66];                // final h (fp32)
    __shared__ __align__(16) float dred[16][16];               // dsum partials

    using io = IO<BF16>;

    // ---- B fragments: h-part duplicates each W row twice (k'=2u+p) ----
    bf16x8 Bh[3][4];   // [gate z/r/hh][K-tile]
#pragma unroll
    for (int gt = 0; gt < 3; ++gt)
#pragma unroll
        for (int tt = 0; tt < 4; ++tt)
#pragma unroll
            for (int j = 0; j < 8; ++j) {
                const int row = 16 * tt + 4 * q + (j >> 1);
                Bh[gt][tt][j] = io::ldb(rk, row * 192 + 64 * gt + u);
            }
    bf16x8 Bxz, Bxr, Bxh;   // x-part (rows >=15 zero; A rows >=16 also zero)
#pragma unroll
    for (int j = 0; j < 8; ++j) {
        const int k0 = 8 * q + j;
        const bool vx = (k0 < 15);
        Bxz[j] = vx ? io::ldb(gk, k0 * 192 + u)       : us2bf(0);
        Bxr[j] = vx ? io::ldb(gk, k0 * 192 + 64 + u)  : us2bf(0);
        Bxh[j] = vx ? io::ldb(gk, k0 * 192 + 128 + u) : us2bf(0);
    }
    // biases (accumulator init)
    const float bz_  = io::ld(gb, u)        + io::ld(gb, 192 + u);
    const float br_  = io::ld(gb, 64 + u)   + io::ld(gb, 192 + 64 + u);
    const float bah_ = io::ld(gb, 192 + 128 + u);   // b_r[h]
    const float bax_ = io::ld(gb, 128 + u);         // b_i[h]

    // zero-init hsm (h0=0) and xt (persistent zero pad ch>=16)
    {
        unsigned int* hz = (unsigned int*)&hsm[0][0][0];
        for (int i = tid; i < 2 * 16 * 132 / 2; i += 256) hz[i] = 0u;
        unsigned int* xz = (unsigned int*)&xt[0][0][0][0];
        for (int i = tid; i < 2 * 16 * 16 * 36 / 2; i += 256) xz[i] = 0u;
    }
    float hreg[4] = {0.0f, 0.0f, 0.0f, 0.0f};

    // staging mapping: thread -> (batch sb, s2-row sp)
    const int sb = tid >> 4, sp = tid & 15;
    const size_t gbase = (size_t)(16 * g + sb) * 16384;
    uint4 rA, rB;
    stagex<BF16>(inp, gbase + (size_t)sp * 16, rA, rB);   // tile 0
    float dsumP = 0.0f;
    __syncthreads();   // zero-init visible

#pragma unroll 1
    for (int t = 0; t < 64; ++t) {
        // stage tile t: 16 shorts ch0..15 as 4x 8B writes (8B-aligned rows)
        {
            unsigned short* xr = &xt[t & 1][sp][sb][0];
            *(uint2*)(xr + 0)  = make_uint2(rA.x, rA.y);
            *(uint2*)(xr + 4)  = make_uint2(rA.z, rA.w);
            *(uint2*)(xr + 8)  = make_uint2(rB.x, rB.y);
            *(uint2*)(xr + 12) = make_uint2(rB.z, rB.w);
        }
        dsumP += (float)us2bf((unsigned short)(rB.w >> 16));   // ch15
        __syncthreads();
        if (t < 63) stagex<BF16>(inp, gbase + (size_t)(16 * (t + 1) + sp) * 16, rA, rB);

#pragma unroll 2
        for (int s2 = 0; s2 < 16; ++s2) {
            const int s   = 16 * t + s2;
            const int par = s & 1;
            const int pn  = par ^ 1;

            // ---- A(h): 4 K-tiles, each 8 contiguous shorts (2x b64) ----
            const unsigned short* hrow = &hsm[par][lc][0];
            bf16x8 Ah[4];
#pragma unroll
            for (int tt = 0; tt < 4; ++tt) {
                uint2 e0 = *(const uint2*)(hrow + 32 * tt + 8 * q);
                uint2 e1 = *(const uint2*)(hrow + 32 * tt + 8 * q + 4);
                union { uint4 u4; bf16x8 v; } cc;
                cc.u4 = make_uint4(e0.x, e0.y, e1.x, e1.y);
                Ah[tt] = cc.v;
            }
            // ---- A(x): raw shorts (rows >=16 are persistent zeros) ----
            const unsigned short* xrow = &xt[t & 1][s2][lc][0];
            uint2 xa0 = *(const uint2*)(xrow + 8 * q);
            uint2 xa1 = *(const uint2*)(xrow + 8 * q + 4);
            union { uint4 u4; bf16x8 v; } xc;
            xc.u4 = make_uint4(xa0.x, xa0.y, xa1.x, xa1.y);
            const bf16x8 Ax = xc.v;
            asm volatile("" ::: "memory");

            // ---- 15 MFMAs, 7 accumulators (chains depth <=3) ----
            f32x4 azA, azB, arA, arB, ahA, ahB, axA;
#pragma unroll
            for (int i = 0; i < 4; ++i) {
                azA[i] = bz_;  azB[i] = 0.0f;
                arA[i] = br_;  arB[i] = 0.0f;
                ahA[i] = bah_; ahB[i] = 0.0f;
                axA[i] = bax_;
            }
            azA = __builtin_amdgcn_mfma_f32_16x16x32_bf16(Ah[0], Bh[0][0], azA, 0, 0, 0);
            arA = __builtin_amdgcn_mfma_f32_16x16x32_bf16(Ah[0], Bh[1][0], arA, 0, 0, 0);
            ahA = __builtin_amdgcn_mfma_f32_16x16x32_bf16(Ah[0], Bh[2][0], ahA, 0, 0, 0);
            azB = __builtin_amdgcn_mfma_f32_16x16x32_bf16(Ah[2], Bh[0][2], azB, 0, 0, 0);
            arB = __builtin_amdgcn_mfma_f32_16x16x32_bf16(Ah[2], Bh[1][2], arB, 0, 0, 0);
            ahB = __builtin_amdgcn_mfma_f32_16x16x32_bf16(Ah[2], Bh[2][2], ahB, 0, 0, 0);
            azA = __builtin_amdgcn_mfma_f32_16x16x32_bf16(Ah[1], Bh[0][1], azA, 0, 0, 0);
            arA = __builtin_amdgcn_mfma_f32_16x16x32_bf16(Ah[1], Bh[1][1], arA, 0, 0, 0);
            ahA = __builtin_amdgcn_mfma_f32_16x16x32_bf16(Ah[1], Bh[2][1], ahA, 0, 0, 0);
            azB = __builtin_amdgcn_mfma_f32_16x16x32_bf16(Ah[3], Bh[0][3], azB, 0, 0, 0);
            arB = __builtin_amdgcn_mfma_f32_16x16x32_bf16(Ah[3], Bh[1][3], arB, 0, 0, 0);
            ahB = __builtin_amdgcn_mfma_f32_16x16x32_bf16(Ah[3], Bh[2][3], ahB, 0, 0, 0);
            azB = __builtin_amdgcn_mfma_f32_16x16x32_bf16(Ax, Bxz, azB, 0, 0, 0);
            arB = __builtin_amdgcn_mfma_f32_16x16x32_bf16(Ax, Bxr, arB, 0, 0, 0);
            axA = __builtin_amdgcn_mfma_f32_16x16x32_bf16(Ax, Bxh, axA, 0, 0, 0);

            const f32x4 AZ = azA + azB;
            const f32x4 AR = arA + arB;
            const f32x4 AH = ahA + ahB;

            // ---- nonlinearity + hi/lo split at write (lane: batch 4q+i, unit u) ----
#pragma unroll
            for (int i = 0; i < 4; ++i) {
                const float z   = __builtin_amdgcn_rcpf(1.0f + __expf(-AZ[i]));
                const float r   = __builtin_amdgcn_rcpf(1.0f + __expf(-AR[i]));
                const float pre = fmaf(r, AH[i], axA[i]);
                const float e2  = __expf(2.0f * pre);
                const float th  = 1.0f - 2.0f * __builtin_amdgcn_rcpf(e2 + 1.0f);
                const float h   = fmaf(z, hreg[i] - th, th);
                hreg[i] = h;
                HBU c1; c1.b = __float2bfloat16(h);
                FIU fh; fh.u = (unsigned int)c1.s << 16;
                HBU c2; c2.b = __float2bfloat16(h - fh.f);
                const unsigned int dw = (unsigned int)c1.s | ((unsigned int)c2.s << 16);
                *(unsigned int*)&hsm[pn][4 * q + i][2 * u] = dw;
            }
            __syncthreads();           // the ONE barrier per step
        }
    }

    // ---- epilogue: delta effect + dense head ----
#pragma unroll
    for (int i = 0; i < 4; ++i) heb[4 * q + i][u] = hreg[i];
    dred[sp][sb] = dsumP;
    __syncthreads();

    const int hb = tid >> 4, hr = tid & 15;   // (batch, j-part)
    float dsb = 0.0f;
#pragma unroll
    for (int pp = 0; pp < 16; ++pp) dsb += dred[pp][hb];
    const float de = io::ld(Tp, 0) * dsb * (1.0f / 1024.0f);

    float accj[4];
#pragma unroll
    for (int jj = 0; jj < 4; ++jj) accj[jj] = io::ld(b1v, hr + 16 * jj);
    for (int uu = 0; uu < 64; ++uu) {
        const float sv = heb[hb][uu] + de;
#pragma unroll
        for (int jj = 0; jj < 4; ++jj)
            accj[jj] = fmaf(sv, io::ld(w1, uu * 64 + hr + 16 * jj), accj[jj]);
    }
    float part = 0.0f;
#pragma unroll
    for (int jj = 0; jj < 4; ++jj) {
        const int j = hr + 16 * jj;
        float aa = fmaxf(accj[jj], 0.0f);                      // ReLU
        const float inv = rsqrtf(io::ld(vav, j) + 0.001f);     // BN_EPS
        aa = fmaf((aa - io::ld(muv, j)) * inv, io::ld(gam, j), io::ld(bet, j));
        part = fmaf(aa, io::ld(w2, j), part);
    }
    part += __shfl_xor(part, 1, 64);
    part += __shfl_xor(part, 2, 64);
    part += __shfl_xor(part, 4, 64);
    part += __shfl_xor(part, 8, 64);
    if (hr == 0) io::st(out, 16 * g + hb, part + io::ld(bb2, 0));
}

extern "C" void kernel_launch(void* const* d_in, const int* in_sizes, int n_in,
                              void* d_out, int out_size, void* d_ws, size_t ws_size,
                              hipStream_t stream)
{
    const void* inp = d_in[0];   // (512,1024,16)
    const void* gk  = d_in[1];   // (15,192)
    const void* rk  = d_in[2];   // (64,192)
    const void* gb  = d_in[3];   // (2,192)
    const void* w1  = d_in[4];   // (64,64)
    const void* b1v = d_in[5];   // (64,)
    const void* gam = d_in[6];
    const void* bet = d_in[7];
    const void* muv = d_in[8];
    const void* vav = d_in[9];
    const void* w2  = d_in[10];  // (64,1)
    const void* bb2 = d_in[11];  // (1,)
    const void* Tp  = d_in[12];  // (1,)

    int* flag = (int*)d_ws;
    detect_dtype_kernel<<<dim3(1), dim3(1), 0, stream>>>(rk, flag);
    gru_full_kernel<true ><<<dim3(32), dim3(256), 0, stream>>>(
        inp, gk, rk, gb, w1, b1v, gam, bet, muv, vav, w2, bb2, Tp, flag, d_out);
    gru_full_kernel<false><<<dim3(32), dim3(256), 0, stream>>>(
        inp, gk, rk, gb, w1, b1v, gam, bet, muv, vav, w2, bb2, Tp, flag, d_out);
}